// Round 1
// baseline (100.815 us; speedup 1.0000x reference)
//
#include <hip/hip_runtime.h>

// SegmentTree prefix-sum sampling, 2^24 leaves, 65536 queries.
// Fanout-8 tree: store only bottom-levels 3,6,9,12,15,18,21 + root (~9.6 MB ws).
// All sums use the exact binary-tree association of the reference
// (((x0+x1)+(x2+x3))+((x4+x5)+(x6+x7))) so the descent is bit-identical
// to the fp32 jax reference. No fast-math.

#define LEAVES_LG 24
#define BATCH_N   65536

// ws offsets in floats (all 16B-aligned for float4 loads)
#define OFF_ROOT 0
#define OFF_L21  4         // 8
#define OFF_L18  16        // 64
#define OFF_L15  80        // 512
#define OFF_L12  592       // 4096
#define OFF_L9   4688      // 32768
#define OFF_L6   37456     // 262144
#define OFF_L3   299600    // 2097152  -> end 2396752 floats (~9.59 MB)

__device__ __forceinline__ float sum8_exact(float x0, float x1, float x2, float x3,
                                            float x4, float x5, float x6, float x7) {
    // matches reference build: level+3 node = ((x0+x1)+(x2+x3))+((x4+x5)+(x6+x7))
    return ((x0 + x1) + (x2 + x3)) + ((x4 + x5) + (x6 + x7));
}

// leaves -> L3, L6, L9.  grid 8192 x 256, each thread folds 8 contiguous leaves.
__global__ __launch_bounds__(256) void build_lo(const float* __restrict__ leaf,
                                                float* __restrict__ ws) {
    __shared__ float sm[256];
    __shared__ float sm2[32];
    const int t = threadIdx.x;
    const size_t gid = (size_t)blockIdx.x * 256 + t;
    const float4* lv = reinterpret_cast<const float4*>(leaf) + gid * 2;
    float4 a = lv[0];
    float4 b = lv[1];
    float s3 = sum8_exact(a.x, a.y, a.z, a.w, b.x, b.y, b.z, b.w);
    ws[OFF_L3 + gid] = s3;
    sm[t] = s3;
    __syncthreads();
    if (t < 32) {
        float s6 = sum8_exact(sm[8*t+0], sm[8*t+1], sm[8*t+2], sm[8*t+3],
                              sm[8*t+4], sm[8*t+5], sm[8*t+6], sm[8*t+7]);
        ws[OFF_L6 + (size_t)blockIdx.x * 32 + t] = s6;
        sm2[t] = s6;
    }
    __syncthreads();
    if (t < 4) {
        float s9 = sum8_exact(sm2[8*t+0], sm2[8*t+1], sm2[8*t+2], sm2[8*t+3],
                              sm2[8*t+4], sm2[8*t+5], sm2[8*t+6], sm2[8*t+7]);
        ws[OFF_L9 + (size_t)blockIdx.x * 4 + t] = s9;
    }
}

// L9 -> L12, L15, L18.  grid 16 x 256.
__global__ __launch_bounds__(256) void build_mid(float* __restrict__ ws) {
    __shared__ float sm[256];
    __shared__ float sm2[32];
    const int t = threadIdx.x;
    const int b = blockIdx.x;
    const float4* in = reinterpret_cast<const float4*>(ws + OFF_L9 + (size_t)b * 2048) + (size_t)t * 2;
    float4 x = in[0];
    float4 y = in[1];
    float s12 = sum8_exact(x.x, x.y, x.z, x.w, y.x, y.y, y.z, y.w);
    ws[OFF_L12 + (size_t)b * 256 + t] = s12;
    sm[t] = s12;
    __syncthreads();
    if (t < 32) {
        float s15 = sum8_exact(sm[8*t+0], sm[8*t+1], sm[8*t+2], sm[8*t+3],
                               sm[8*t+4], sm[8*t+5], sm[8*t+6], sm[8*t+7]);
        ws[OFF_L15 + (size_t)b * 32 + t] = s15;
        sm2[t] = s15;
    }
    __syncthreads();
    if (t < 4) {
        float s18 = sum8_exact(sm2[8*t+0], sm2[8*t+1], sm2[8*t+2], sm2[8*t+3],
                               sm2[8*t+4], sm2[8*t+5], sm2[8*t+6], sm2[8*t+7]);
        ws[OFF_L18 + (size_t)b * 4 + t] = s18;
    }
}

// L18 -> L21, root.  1 block x 64.
__global__ __launch_bounds__(64) void build_top(float* __restrict__ ws) {
    __shared__ float sm[8];
    const int t = threadIdx.x;
    if (t < 8) {
        const float* in = ws + OFF_L18 + t * 8;
        float s21 = sum8_exact(in[0], in[1], in[2], in[3], in[4], in[5], in[6], in[7]);
        ws[OFF_L21 + t] = s21;
        sm[t] = s21;
    }
    __syncthreads();
    if (t == 0) {
        ws[OFF_ROOT] = sum8_exact(sm[0], sm[1], sm[2], sm[3], sm[4], sm[5], sm[6], sm[7]);
    }
}

// One fanout-8 step: read children c0..c7 of node p, do 3 bit-exact binary
// descents in-register, update p and running value v.  picked = chosen child.
__device__ __forceinline__ void step8(const float* __restrict__ base, int& p, float& v,
                                      float& picked) {
    const float4* q = reinterpret_cast<const float4*>(base + (size_t)p * 8);
    float4 x = q[0];
    float4 y = q[1];
    // exact reconstruction of the two intermediate tree levels on the path
    float n0 = x.x + x.y;          // level+1 left-left
    float n2 = y.x + y.y;          // level+1 right-left
    float t2 = n0 + (x.z + x.w);   // level+2 left = (c0+c1)+(c2+c3)
    int ia = t2 < v;
    if (ia) v -= t2;
    float pn = ia ? n2 : n0;
    int ib = pn < v;
    if (ib) v -= pn;
    float ce = ia ? (ib ? y.z : y.x) : (ib ? x.z : x.x);
    float co = ia ? (ib ? y.w : y.y) : (ib ? x.w : x.y);
    int ic = ce < v;
    if (ic) v -= ce;
    picked = ic ? co : ce;
    p = p * 8 + ia * 4 + ib * 2 + ic;
}

// 8-step descent per query.  grid 256 x 256.
__global__ __launch_bounds__(256) void descend(const float* __restrict__ leaf,
                                               const float* __restrict__ frac,
                                               const float* __restrict__ ws,
                                               float* __restrict__ out) {
    const int tid = blockIdx.x * 256 + threadIdx.x;
    float v = frac[tid] * ws[OFF_ROOT];
    int p = 0;
    float picked = 0.0f;
    step8(ws + OFF_L21, p, v, picked);
    step8(ws + OFF_L18, p, v, picked);
    step8(ws + OFF_L15, p, v, picked);
    step8(ws + OFF_L12, p, v, picked);
    step8(ws + OFF_L9,  p, v, picked);
    step8(ws + OFF_L6,  p, v, picked);
    step8(ws + OFF_L3,  p, v, picked);
    step8(leaf,         p, v, picked);   // final picked == leaf[index]
    out[tid] = (float)p;                 // index output (heap idx - BOUND == p)
    out[BATCH_N + tid] = picked;         // priority output
}

extern "C" void kernel_launch(void* const* d_in, const int* in_sizes, int n_in,
                              void* d_out, int out_size, void* d_ws, size_t ws_size,
                              hipStream_t stream) {
    const float* leaf = (const float*)d_in[0];
    const float* frac = (const float*)d_in[1];
    float* out = (float*)d_out;
    float* ws  = (float*)d_ws;

    hipLaunchKernelGGL(build_lo,  dim3(8192), dim3(256), 0, stream, leaf, ws);
    hipLaunchKernelGGL(build_mid, dim3(16),   dim3(256), 0, stream, ws);
    hipLaunchKernelGGL(build_top, dim3(1),    dim3(64),  0, stream, ws);
    hipLaunchKernelGGL(descend,   dim3(256),  dim3(256), 0, stream, leaf, frac, ws, out);
}

// Round 2
// 97.972 us; speedup vs baseline: 1.0290x; 1.0290x over previous
//
#include <hip/hip_runtime.h>

// SegmentTree prefix-sum sampling, 2^24 leaves, 65536 queries.
// Fanout-16 tree: store levels with 16, 256, 4096, 65536, 1048576 nodes + root
// (~4.5 MB ws). Every stored value and every reconstructed intermediate uses
// the exact pairwise association of the reference build
// (((a+b)+(c+d))+((e+f)+(g+h)))... so the binary descent is bit-identical to
// the fp32 jax reference. No fast-math.
//
// Descent: 6 dependent 64B loads per query (4 binary levels resolved per step,
// final step's line IS the leaf gather).

#define BATCH_N 65536

// ws offsets in floats (all 64B-aligned)
#define OFF_ROOT 0
#define OFF_A 16       // 16 nodes   (children of root)
#define OFF_B 32       // 256
#define OFF_C 288      // 4096
#define OFF_D 4384     // 65536
#define OFF_E 69920    // 1048576   -> end 1118496 floats (~4.47 MB)

__device__ __forceinline__ float sum16_exact(float4 A, float4 B, float4 C, float4 D) {
    // 4 pairwise levels, matching the reference's reshape(-1,2).sum build
    float n0 = A.x + A.y, n1 = A.z + A.w, n2 = B.x + B.y, n3 = B.z + B.w;
    float n4 = C.x + C.y, n5 = C.z + C.w, n6 = D.x + D.y, n7 = D.z + D.w;
    float m0 = n0 + n1, m1 = n2 + n3, m2 = n4 + n5, m3 = n6 + n7;
    return (m0 + m1) + (m2 + m3);
}

__device__ __forceinline__ float sum16_exact_s(const float* __restrict__ x) {
    float n0 = x[0] + x[1],  n1 = x[2] + x[3],  n2 = x[4] + x[5],  n3 = x[6] + x[7];
    float n4 = x[8] + x[9],  n5 = x[10] + x[11], n6 = x[12] + x[13], n7 = x[14] + x[15];
    float m0 = n0 + n1, m1 = n2 + n3, m2 = n4 + n5, m3 = n6 + n7;
    return (m0 + m1) + (m2 + m3);
}

// leaves -> E (2^20), D (2^16), C (2^12).  grid 4096 x 256; thread folds 16 leaves.
__global__ __launch_bounds__(256) void build_lo(const float* __restrict__ leaf,
                                                float* __restrict__ ws) {
    __shared__ float smE[256];
    __shared__ float smD[16];
    const int t = threadIdx.x;
    const int b = blockIdx.x;
    const size_t gid = (size_t)b * 256 + t;
    const float4* q = reinterpret_cast<const float4*>(leaf) + gid * 4;
    float4 A = q[0], Bv = q[1], Cv = q[2], Dv = q[3];
    float e = sum16_exact(A, Bv, Cv, Dv);
    ws[OFF_E + gid] = e;
    smE[t] = e;
    __syncthreads();
    if (t < 16) {
        float d = sum16_exact_s(&smE[16 * t]);
        ws[OFF_D + (size_t)b * 16 + t] = d;
        smD[t] = d;
    }
    __syncthreads();
    if (t == 0) {
        ws[OFF_C + b] = sum16_exact_s(smD);
    }
}

// C (4096) -> B (256) -> A (16) -> root.  1 block x 256.
__global__ __launch_bounds__(256) void build_top(float* __restrict__ ws) {
    __shared__ float smB[256];
    __shared__ float smA[16];
    const int t = threadIdx.x;
    const float4* q = reinterpret_cast<const float4*>(ws + OFF_C) + (size_t)t * 4;
    float4 A = q[0], Bv = q[1], Cv = q[2], Dv = q[3];
    float bnode = sum16_exact(A, Bv, Cv, Dv);
    ws[OFF_B + t] = bnode;
    smB[t] = bnode;
    __syncthreads();
    if (t < 16) {
        float anode = sum16_exact_s(&smB[16 * t]);
        ws[OFF_A + t] = anode;
        smA[t] = anode;
    }
    __syncthreads();
    if (t == 0) {
        ws[OFF_ROOT] = sum16_exact_s(smA);
    }
}

// One fanout-16 step: read 16 children of node p (one 64B line), resolve 4
// bit-exact binary descent levels in-register. picked = chosen child value.
__device__ __forceinline__ void step16(const float* __restrict__ base, int& p, float& v,
                                       float& picked) {
    const float4* q = reinterpret_cast<const float4*>(base + (size_t)p * 16);
    float4 A = q[0], B = q[1], C = q[2], D = q[3];
    // reconstruct intermediate binary levels with the build's exact association
    float n0 = A.x + A.y, n2 = B.x + B.y, n4 = C.x + C.y, n6 = D.x + D.y;
    float m0 = n0 + (A.z + A.w);   // (c0+c1)+(c2+c3)
    float m2 = n4 + (C.z + C.w);   // (c8+c9)+(c10+c11)
    float t0 = m0 + (n2 + (B.z + B.w));  // left child at top binary level

    int ia = t0 < v;  if (ia) v -= t0;
    float mm = ia ? m2 : m0;
    int ib = mm < v;  if (ib) v -= mm;
    float nn = ia ? (ib ? n6 : n4) : (ib ? n2 : n0);
    int ic = nn < v;  if (ic) v -= nn;
    // even child c_{8ia+4ib+2ic} and odd child c_{...+1}
    float se0 = ia ? C.x : A.x, se1 = ia ? C.z : A.z;
    float se2 = ia ? D.x : B.x, se3 = ia ? D.z : B.z;
    float so0 = ia ? C.y : A.y, so1 = ia ? C.w : A.w;
    float so2 = ia ? D.y : B.y, so3 = ia ? D.w : B.w;
    float ce = ic ? (ib ? se3 : se1) : (ib ? se2 : se0);
    float co = ic ? (ib ? so3 : so1) : (ib ? so2 : so0);
    int id = ce < v;  if (id) v -= ce;
    picked = id ? co : ce;
    p = p * 16 + ia * 8 + ib * 4 + ic * 2 + id;
}

// 6-step descent per query.  grid 256 x 256.
__global__ __launch_bounds__(256) void descend(const float* __restrict__ leaf,
                                               const float* __restrict__ frac,
                                               const float* __restrict__ ws,
                                               float* __restrict__ out) {
    const int tid = blockIdx.x * 256 + threadIdx.x;
    float v = frac[tid] * ws[OFF_ROOT];
    int p = 0;
    float picked = 0.0f;
    step16(ws + OFF_A, p, v, picked);
    step16(ws + OFF_B, p, v, picked);
    step16(ws + OFF_C, p, v, picked);
    step16(ws + OFF_D, p, v, picked);
    step16(ws + OFF_E, p, v, picked);
    step16(leaf,       p, v, picked);   // final picked == leaf[index]
    out[tid] = (float)p;                // exact: p < 2^24
    out[BATCH_N + tid] = picked;
}

extern "C" void kernel_launch(void* const* d_in, const int* in_sizes, int n_in,
                              void* d_out, int out_size, void* d_ws, size_t ws_size,
                              hipStream_t stream) {
    const float* leaf = (const float*)d_in[0];
    const float* frac = (const float*)d_in[1];
    float* out = (float*)d_out;
    float* ws  = (float*)d_ws;

    hipLaunchKernelGGL(build_lo,  dim3(4096), dim3(256), 0, stream, leaf, ws);
    hipLaunchKernelGGL(build_top, dim3(1),    dim3(256), 0, stream, ws);
    hipLaunchKernelGGL(descend,   dim3(256),  dim3(256), 0, stream, leaf, frac, ws, out);
}